// Round 31
// baseline (145.546 us; speedup 1.0000x reference)
//
#include <hip/hip_runtime.h>
#include <stdint.h>
#include <limits.h>

// StackMachineCell — fused, scalar producer v2 (round 31).
// r30 win (XCD-local L2 warmup: e2e 152->141) retro-explains r27's 172:
// the scalar chain ran COLD (pre-warmup) and its per-step publish ds_write
// serialized with s_load on lgkmcnt. This round de-confounds r27:
//  - warmup kept (consumers sweep the 1MB u32 LUT first);
//  - publish batched: 4 u32 accumulate 8 steps, ONE ds_write_b128/8 steps;
//  - inputs via 2 uniform ds_read_b128 per 8-step group (broadcast);
//  - inner 8-step loop unrolled, outer dynamic (no I$ thrash);
//  - bitplane SGPR stack + SALU chain (r27-PROVEN correct) -> scalar pipe,
//    immune to consumer VALU contention (why r25/r28/r29 regressed).
// Consumers byte-identical to r30 (flag poll, nt stores).
// ws: Mm32@0 | Ms32@17408 | Mb32@50176 | MmT@115712 | MsT@133120 |
//     lut u32 @165888 (1MB) (total 1214464 B; guarded).

#define TT 512
#define BB 512
#define HH 128
#define NSs 64
#define NMm 34
#define NBb 128

typedef unsigned short u16;
typedef unsigned long long u64;
typedef float f2 __attribute__((ext_vector_type(2)));

// ---- precompute M tables (f64 accumulate, f32 store; + transposed copies)
__global__ __launch_bounds__(256) void precompute_M(
    const float* __restrict__ embed,
    const float* __restrict__ Wm, const float* __restrict__ bm,
    const float* __restrict__ Wb, const float* __restrict__ bb,
    const float* __restrict__ Ws, const float* __restrict__ bs,
    float* __restrict__ Mm32, float* __restrict__ Ms32,
    float* __restrict__ Mb32, float* __restrict__ MmT,
    float* __restrict__ MsT) {
  __shared__ double e[HH];
  const int v = blockIdx.x;
  const int tid = threadIdx.x;  // 256
  if (tid < HH) e[tid] = (double)embed[v * HH + tid];
  __syncthreads();
  if (tid < NMm) {
    const int j = tid;
    double acc = 0.0;
    for (int h = 0; h < HH; ++h) acc += e[h] * (double)Wm[h * NMm + j];
    const float r = (float)(acc + (double)bm[j]);
    Mm32[v * NMm + j] = r;
    MmT[j * 128 + v] = r;
  } else if (tid < NMm + NSs) {
    const int j = tid - NMm;
    double acc = 0.0;
    for (int h = 0; h < HH; ++h) acc += e[h] * (double)Ws[h * NSs + j];
    const float r = (float)(acc + (double)bs[j]);
    Ms32[v * NSs + j] = r;
    MsT[j * 128 + v] = r;
  } else if (tid < NMm + NSs + NBb) {
    const int j = tid - NMm - NSs;
    double acc = 0.0;
    for (int h = 0; h < HH; ++h) acc += e[h] * (double)Wb[h * NBb + j];
    Mb32[v * NBb + j] = (float)(acc + (double)bb[j]);
  }
}

// ---- build decision LUT (u32): block = (s,r) pair, thread = v.
// Bit-identical decisions to r12-r30. Layout lut[(s*32+r)*128 + v].
__global__ __launch_bounds__(128) void build_lut(
    const float* __restrict__ Wm, const float* __restrict__ Ws,
    const float* __restrict__ MmT, const float* __restrict__ MsT,
    unsigned* __restrict__ lut) {
  __shared__ float wms[NMm], wmr[NMm], wss[NSs], wsr[NSs];  // 784 B
  const int s = blockIdx.x >> 5;    // 0..63
  const int r = blockIdx.x & 31;    // 0..31
  const int tid = threadIdx.x;      // 128 = one v per thread
  if (tid < NMm) {
    wms[tid] = Wm[(128 + s) * NMm + tid];
    wmr[tid] = Wm[(192 + r) * NMm + tid];
  }
  if (tid < NSs) {
    wss[tid] = Ws[(128 + s) * NSs + tid];
    wsr[tid] = Ws[(192 + r) * NSs + tid];
  }
  __syncthreads();

  const int v = tid;
  int bestm = INT_MIN, act = 0;
#pragma unroll
  for (int j = 0; j < NMm; ++j) {
    const double val = (double)MmT[j * 128 + v] + (double)wms[j] + (double)wmr[j];
    const int iv = (int)(val * 67108864.0);
    if (iv > bestm) { bestm = iv; act = j; }
  }
  int bests = INT_MIN, ns = 0;
#pragma unroll
  for (int j = 0; j < NSs; ++j) {
    const double val = (double)MsT[j * 128 + v] + (double)wss[j] + (double)wsr[j];
    const int iv = (int)(val * 67108864.0);
    if (iv > bests) { bests = iv; ns = j; }
  }
  lut[(unsigned)blockIdx.x * 128 + v] = (unsigned)(act | (ns << 6));
}

// ---- fused: 512 blocks x 512 threads, ONE chain per block.
// Wave 0 = producer (scalar chain, bitplane stack, batched publish);
// waves 1-7 = consumers (warmup sweep, rows t mod 7, nt stores).
__global__ __launch_bounds__(512, 1) void sm_fused(
    const int* __restrict__ x, const int* __restrict__ tact,
    const int* __restrict__ tstate, const int* __restrict__ forc,
    const unsigned* __restrict__ lut,
    const float* __restrict__ Wm, const float* __restrict__ Wb,
    const float* __restrict__ Ws,
    const float* __restrict__ Mm32, const float* __restrict__ Ms32,
    const float* __restrict__ Mb32, float* __restrict__ out) {
  __shared__ unsigned sPk[TT];          // 2048 B
  __shared__ volatile u16 trajL[TT];    // 1024 B (flag+data in one u16)
  const int tid = threadIdx.x;
  const int b = blockIdx.x;
  for (int t = tid; t < TT; t += 512) {
    const int g = t * BB + b;
    sPk[t] = (unsigned)x[g] | ((unsigned)tact[g] << 8) |
             ((unsigned)tstate[g] << 16) | ((unsigned)forc[g] << 24);
    trajL[t] = 0xFFFFu;
  }
  __syncthreads();  // last barrier; roles diverge below

  const int lane = tid & 63;
  const int w = tid >> 6;

  if (w == 0) {
    // ===== producer: scalar chain (r27-proven), batched publish =========
    __builtin_amdgcn_s_setprio(1);
    u64 pl0 = 0, pl1 = 0, pl2 = 0, pl3 = 0, pl4 = 0;  // stack bitplanes
    int ptr = 0, rr = 0, s = 0;
    uint4* trajQ = (uint4*)&((u16*)trajL)[0];  // 16B = 8 steps per group

    for (int g = 0; g < TT / 8; ++g) {
      // 8 packed inputs, uniform-address broadcast reads (2 x ds_read_b128)
      const uint4 ia = *(const uint4*)&sPk[g * 8];
      const uint4 ib = *(const uint4*)&sPk[g * 8 + 4];
      unsigned w0 = 0, w1 = 0, w2 = 0, w3 = 0;
#pragma unroll
      for (int k = 0; k < 8; ++k) {
        const unsigned pk = __builtin_amdgcn_readfirstlane(
            k == 0 ? ia.x : k == 1 ? ia.y : k == 2 ? ia.z : k == 3 ? ia.w
            : k == 4 ? ib.x : k == 5 ? ib.y : k == 6 ? ib.z : ib.w);
        const unsigned word = (unsigned)(s | (rr << 8));
        if (k == 0) w0 = word;
        else if (k == 1) w0 |= word << 16;
        else if (k == 2) w1 = word;
        else if (k == 3) w1 |= word << 16;
        else if (k == 4) w2 = word;
        else if (k == 5) w2 |= word << 16;
        else if (k == 6) w3 = word;
        else w3 |= word << 16;

        int act, ns;
        if (pk >> 24) {  // forced: all scalar
          act = (int)((pk >> 8) & 63u);
          ns = (int)((pk >> 16) & 63u);
        } else {
          const int idx = __builtin_amdgcn_readfirstlane(
              s * 4096 + rr * 128 + (int)(pk & 127u));
          const unsigned lv = lut[idx];  // uniform -> s_load, warm L2
          act = (int)(lv & 63u);
          ns = (int)((lv >> 6) & 63u);
        }

        const bool ispush = act >= 2;
        int npn = ptr + (ispush ? 1 : 0) - (act == 1 ? 1 : 0);
        npn = npn < 0 ? 0 : (npn > 63 ? 63 : npn);
        if (ispush) {  // stack[npn] = sym (bit-set in 5 planes, SALU)
          const unsigned sym = (unsigned)(act - 2);
          const u64 m = ~(1ULL << npn);
          pl0 = (pl0 & m) | ((u64)(sym & 1u) << npn);
          pl1 = (pl1 & m) | ((u64)((sym >> 1) & 1u) << npn);
          pl2 = (pl2 & m) | ((u64)((sym >> 2) & 1u) << npn);
          pl3 = (pl3 & m) | ((u64)((sym >> 3) & 1u) << npn);
          pl4 = (pl4 & m) | ((u64)((sym >> 4) & 1u) << npn);
        }
        // rr = stack[npn] (bit-extract, SALU) — r27-proven semantics
        rr = (int)(((pl0 >> npn) & 1) | (((pl1 >> npn) & 1) << 1) |
                   (((pl2 >> npn) & 1) << 2) | (((pl3 >> npn) & 1) << 3) |
                   (((pl4 >> npn) & 1) << 4));
        ptr = npn;
        s = ns;
      }
      // publish 8 steps at once (one ds_write_b128; lane 0 only)
      if (lane == 0) {
        uint4 v4; v4.x = w0; v4.y = w1; v4.z = w2; v4.w = w3;
        trajQ[g] = v4;
      }
    }
  } else {
    // ======= consumer: warm local-XCD L2 (1MB u32 LUT), then rows =======
    const int j = w - 1;   // 0..6
    const int cidx = j * 64 + lane;  // 0..447
    {
      const uint4* lut4 = (const uint4*)lut;
      unsigned acc = 0;
      for (int i = cidx; i < 65536; i += 448) {
        const uint4 vv = lut4[i];
        acc ^= vv.x ^ vv.y ^ vv.z ^ vv.w;
      }
      asm volatile("" : : "v"(acc));  // keep sweep alive (no DCE)
    }

    float* outLM = out;                                  // [T,B,34]
    float* outLB = out + (size_t)TT * BB * NMm;          // [T,B,128]
    float* outLS = out + (size_t)TT * BB * (NMm + NBb);  // [T,B,64]

    for (int t = j; t < TT; t += 7) {
      int pr = trajL[t];
      while (pr == 0xFFFF) {            // flag: row not yet published
        __builtin_amdgcn_s_sleep(4);
        pr = trajL[t];
      }
      const unsigned pk = sPk[t];
      const int xv = (int)(pk & 127u);
      const int s = pr & 255;
      const int r = pr >> 8;
      const int rs = 128 + s, rr = 192 + r;
      const int row = t * BB + b;
      if (lane < NMm)
        __builtin_nontemporal_store(
            Mm32[xv * NMm + lane] + Wm[rs * NMm + lane] + Wm[rr * NMm + lane],
            &outLM[(size_t)row * NMm + lane]);
      __builtin_nontemporal_store(
          Ms32[xv * NSs + lane] + Ws[rs * NSs + lane] + Ws[rr * NSs + lane],
          &outLS[(size_t)row * NSs + lane]);
      const f2 mb  = *(const f2*)&Mb32[xv * NBb + 2 * lane];
      const f2 wbs = *(const f2*)&Wb[rs * NBb + 2 * lane];
      const f2 wbr = *(const f2*)&Wb[rr * NBb + 2 * lane];
      f2 o;
      o.x = mb.x + wbs.x + wbr.x;   // same per-element add order as r14-r30
      o.y = mb.y + wbs.y + wbr.y;
      __builtin_nontemporal_store(o, (f2*)&outLB[(size_t)row * NBb + 2 * lane]);
    }
  }
}

extern "C" void kernel_launch(void* const* d_in, const int* in_sizes, int n_in,
                              void* d_out, int out_size, void* d_ws, size_t ws_size,
                              hipStream_t stream) {
  if (ws_size < 1214464) return;  // signature: absmax 0.3457 -> ws too small

  const int* x     = (const int*)d_in[0];
  const int* tactp = (const int*)d_in[1];
  const int* tstp  = (const int*)d_in[2];
  const int* forcp = (const int*)d_in[3];
  const float* embed = (const float*)d_in[4];
  const float* Wm = (const float*)d_in[5];
  const float* bm = (const float*)d_in[6];
  const float* Wb = (const float*)d_in[7];
  const float* bb = (const float*)d_in[8];
  const float* Ws = (const float*)d_in[9];
  const float* bs = (const float*)d_in[10];

  char* wsp = (char*)d_ws;
  float* Mm32 = (float*)(wsp);             //   17408 B
  float* Ms32 = (float*)(wsp + 17408);     //   32768 B
  float* Mb32 = (float*)(wsp + 50176);     //   65536 B
  float* MmT  = (float*)(wsp + 115712);    //   17408 B
  float* MsT  = (float*)(wsp + 133120);    //   32768 B
  unsigned* lut = (unsigned*)(wsp + 165888);  // 1048576 B -> total 1214464 B

  precompute_M<<<128, 256, 0, stream>>>(embed, Wm, bm, Wb, bb, Ws, bs,
                                        Mm32, Ms32, Mb32, MmT, MsT);
  build_lut<<<2048, 128, 0, stream>>>(Wm, Ws, MmT, MsT, lut);
  sm_fused<<<512, 512, 0, stream>>>(x, tactp, tstp, forcp, lut,
                                    Wm, Wb, Ws, Mm32, Ms32, Mb32,
                                    (float*)d_out);
}

// Round 32
// 143.587 us; speedup vs baseline: 1.0136x; 1.0136x over previous
//
#include <hip/hip_runtime.h>
#include <stdint.h>
#include <limits.h>

// StackMachineCell — fused, register-resident inputs (round 32).
// r31's scalar chain lost again (145.5 vs r30's 140.9) -> r30 is the base.
// Remaining mechanism: r30's producer issues THREE DS ops per step
// (sPk prefetch ds_read + publish ds_write + ds_bpermute); DS ops serialize
// on the LDS pipe (~60cy each) and lgkmcnt waits order them together.
// This round: preload all 512 packed inputs into 8 VGPRs (q0..q7) once;
// per-step fetch via v_readlane (VALU, not DS; static reg select by 8-way
// unroll, uniform lane index) -> DS ops/step 3->2, rotation movs gone.
// Warmup sweep, u16 LUT, flag publish, bpermute, consumers: byte-identical
// to r30 (PASSED, e2e 140.9, absmax 0.0009765625).
// ws: Mm32@0 | Ms32@17408 | Mb32@50176 | MmT@115712 | MsT@133120 |
//     lut@165888  (total 690176 B; guarded).

#define TT 512
#define BB 512
#define HH 128
#define NSs 64
#define NMm 34
#define NBb 128

typedef unsigned short u16;
typedef float f2 __attribute__((ext_vector_type(2)));

// ---- precompute M tables (f64 accumulate, f32 store; + transposed copies)
__global__ __launch_bounds__(256) void precompute_M(
    const float* __restrict__ embed,
    const float* __restrict__ Wm, const float* __restrict__ bm,
    const float* __restrict__ Wb, const float* __restrict__ bb,
    const float* __restrict__ Ws, const float* __restrict__ bs,
    float* __restrict__ Mm32, float* __restrict__ Ms32,
    float* __restrict__ Mb32, float* __restrict__ MmT,
    float* __restrict__ MsT) {
  __shared__ double e[HH];
  const int v = blockIdx.x;
  const int tid = threadIdx.x;  // 256
  if (tid < HH) e[tid] = (double)embed[v * HH + tid];
  __syncthreads();
  if (tid < NMm) {
    const int j = tid;
    double acc = 0.0;
    for (int h = 0; h < HH; ++h) acc += e[h] * (double)Wm[h * NMm + j];
    const float r = (float)(acc + (double)bm[j]);
    Mm32[v * NMm + j] = r;
    MmT[j * 128 + v] = r;
  } else if (tid < NMm + NSs) {
    const int j = tid - NMm;
    double acc = 0.0;
    for (int h = 0; h < HH; ++h) acc += e[h] * (double)Ws[h * NSs + j];
    const float r = (float)(acc + (double)bs[j]);
    Ms32[v * NSs + j] = r;
    MsT[j * 128 + v] = r;
  } else if (tid < NMm + NSs + NBb) {
    const int j = tid - NMm - NSs;
    double acc = 0.0;
    for (int h = 0; h < HH; ++h) acc += e[h] * (double)Wb[h * NBb + j];
    Mb32[v * NBb + j] = (float)(acc + (double)bb[j]);
  }
}

// ---- build decision LUT: block = (s,r) pair, thread = v. Bit-identical
// arithmetic to r12-r31. Layout lut[(s*32+r)*128 + v] (u16).
__global__ __launch_bounds__(128) void build_lut(
    const float* __restrict__ Wm, const float* __restrict__ Ws,
    const float* __restrict__ MmT, const float* __restrict__ MsT,
    u16* __restrict__ lut) {
  __shared__ float wms[NMm], wmr[NMm], wss[NSs], wsr[NSs];  // 784 B
  const int s = blockIdx.x >> 5;    // 0..63
  const int r = blockIdx.x & 31;    // 0..31
  const int tid = threadIdx.x;      // 128 = one v per thread
  if (tid < NMm) {
    wms[tid] = Wm[(128 + s) * NMm + tid];
    wmr[tid] = Wm[(192 + r) * NMm + tid];
  }
  if (tid < NSs) {
    wss[tid] = Ws[(128 + s) * NSs + tid];
    wsr[tid] = Ws[(192 + r) * NSs + tid];
  }
  __syncthreads();

  const int v = tid;
  int bestm = INT_MIN, act = 0;
#pragma unroll
  for (int j = 0; j < NMm; ++j) {
    const double val = (double)MmT[j * 128 + v] + (double)wms[j] + (double)wmr[j];
    const int iv = (int)(val * 67108864.0);
    if (iv > bestm) { bestm = iv; act = j; }
  }
  int bests = INT_MIN, ns = 0;
#pragma unroll
  for (int j = 0; j < NSs; ++j) {
    const double val = (double)MsT[j * 128 + v] + (double)wss[j] + (double)wsr[j];
    const int iv = (int)(val * 67108864.0);
    if (iv > bests) { bests = iv; ns = j; }
  }
  lut[(unsigned)blockIdx.x * 128 + v] = (u16)(act | (ns << 6));
}

// ---- fused: 512 blocks x 512 threads, ONE chain per block.
// Wave 0 = producer (vector chain, register-resident inputs, setprio 1);
// waves 1-7 = consumers (LUT warmup sweep, rows t mod 7, nt stores).
// trajL doubles as progress flag (0xFFFF = not ready; legal <= 0x1F3F).
__global__ __launch_bounds__(512, 1) void sm_fused(
    const int* __restrict__ x, const int* __restrict__ tact,
    const int* __restrict__ tstate, const int* __restrict__ forc,
    const u16* __restrict__ lut,
    const float* __restrict__ Wm, const float* __restrict__ Wb,
    const float* __restrict__ Ws,
    const float* __restrict__ Mm32, const float* __restrict__ Ms32,
    const float* __restrict__ Mb32, float* __restrict__ out) {
  __shared__ unsigned sPk[TT];          // 2048 B
  __shared__ volatile u16 trajL[TT];    // 1024 B (flag+data in one u16)
  const int tid = threadIdx.x;
  const int b = blockIdx.x;
  for (int t = tid; t < TT; t += 512) {
    const int g = t * BB + b;
    sPk[t] = (unsigned)x[g] | ((unsigned)tact[g] << 8) |
             ((unsigned)tstate[g] << 16) | ((unsigned)forc[g] << 24);
    trajL[t] = 0xFFFFu;
  }
  __syncthreads();  // last barrier; roles diverge below

  const int lane = tid & 63;
  const int w = tid >> 6;

  if (w == 0) {
    // ===== producer: r30 chain, inputs in registers (no per-step ds_read)
    __builtin_amdgcn_s_setprio(1);
    // preload all 512 packed inputs: reg g holds steps g*64 + lane
    const unsigned q0 = sPk[0 * 64 + lane], q1 = sPk[1 * 64 + lane];
    const unsigned q2 = sPk[2 * 64 + lane], q3 = sPk[3 * 64 + lane];
    const unsigned q4 = sPk[4 * 64 + lane], q5 = sPk[5 * 64 + lane];
    const unsigned q6 = sPk[6 * 64 + lane], q7 = sPk[7 * 64 + lane];

    int stackv = 0;  // lane i holds stack[i]
    int ptr = 0, rr = 0, s = 0;

#pragma unroll
    for (int g = 0; g < 8; ++g) {
      const unsigned qreg = (g == 0) ? q0 : (g == 1) ? q1
                          : (g == 2) ? q2 : (g == 3) ? q3
                          : (g == 4) ? q4 : (g == 5) ? q5
                          : (g == 6) ? q6 : q7;
      for (int t2 = 0; t2 < 64; ++t2) {
        const int t = g * 64 + t2;
        // per-step input via readlane (VALU->SALU, not DS)
        const unsigned pk =
            (unsigned)__builtin_amdgcn_readlane((int)qreg, t2);

        if (lane == 0) trajL[t] = (u16)(s | (rr << 8));  // publish carry-in

        int act, ns;
        if (pk >> 24) {  // forced: scalar extracts, no LUT
          act = (int)((pk >> 8) & 63u);
          ns = (int)((pk >> 16) & 63u);
        } else {
          const int idx = s * 4096 + rr * 128 + (int)(pk & 127u);
          const int lv = lut[idx];  // vector load — L2-warm after sweep
          act = lv & 63;
          ns = (lv >> 6) & 63;
        }

        const bool ispush = act >= 2;
        int npn = ptr + (ispush ? 1 : 0) - (act == 1 ? 1 : 0);
        npn = npn < 0 ? 0 : (npn > 63 ? 63 : npn);
        if (ispush && lane == npn) stackv = act - 2;
        rr = __builtin_amdgcn_ds_bpermute(npn * 4, stackv);
        ptr = npn;
        s = ns;
      }
    }
  } else {
    // ======= consumer: warm local-XCD L2 with the LUT, then rows ========
    const int j = w - 1;   // 0..6
    const int cidx = j * 64 + lane;  // 0..447
    // LUT warmup sweep: 512KB as 32768 uint4; coalesced per-wave reads.
    {
      const uint4* lut4 = (const uint4*)lut;
      unsigned acc = 0;
      for (int i = cidx; i < 32768; i += 448) {
        const uint4 vv = lut4[i];
        acc ^= vv.x ^ vv.y ^ vv.z ^ vv.w;
      }
      asm volatile("" : : "v"(acc));  // keep the sweep alive (no DCE)
    }

    float* outLM = out;                                  // [T,B,34]
    float* outLB = out + (size_t)TT * BB * NMm;          // [T,B,128]
    float* outLS = out + (size_t)TT * BB * (NMm + NBb);  // [T,B,64]

    for (int t = j; t < TT; t += 7) {
      int pr = trajL[t];
      while (pr == 0xFFFF) {            // flag: row not yet published
        __builtin_amdgcn_s_sleep(4);
        pr = trajL[t];
      }
      const unsigned pk = sPk[t];
      const int xv = (int)(pk & 127u);
      const int s = pr & 255;
      const int r = pr >> 8;
      const int rs = 128 + s, rr = 192 + r;
      const int row = t * BB + b;
      if (lane < NMm)
        __builtin_nontemporal_store(
            Mm32[xv * NMm + lane] + Wm[rs * NMm + lane] + Wm[rr * NMm + lane],
            &outLM[(size_t)row * NMm + lane]);
      __builtin_nontemporal_store(
          Ms32[xv * NSs + lane] + Ws[rs * NSs + lane] + Ws[rr * NSs + lane],
          &outLS[(size_t)row * NSs + lane]);
      const f2 mb  = *(const f2*)&Mb32[xv * NBb + 2 * lane];
      const f2 wbs = *(const f2*)&Wb[rs * NBb + 2 * lane];
      const f2 wbr = *(const f2*)&Wb[rr * NBb + 2 * lane];
      f2 o;
      o.x = mb.x + wbs.x + wbr.x;   // same per-element add order as r14-r31
      o.y = mb.y + wbs.y + wbr.y;
      __builtin_nontemporal_store(o, (f2*)&outLB[(size_t)row * NBb + 2 * lane]);
    }
  }
}

extern "C" void kernel_launch(void* const* d_in, const int* in_sizes, int n_in,
                              void* d_out, int out_size, void* d_ws, size_t ws_size,
                              hipStream_t stream) {
  if (ws_size < 690176) return;  // signature: absmax 0.3457 -> ws too small

  const int* x     = (const int*)d_in[0];
  const int* tactp = (const int*)d_in[1];
  const int* tstp  = (const int*)d_in[2];
  const int* forcp = (const int*)d_in[3];
  const float* embed = (const float*)d_in[4];
  const float* Wm = (const float*)d_in[5];
  const float* bm = (const float*)d_in[6];
  const float* Wb = (const float*)d_in[7];
  const float* bb = (const float*)d_in[8];
  const float* Ws = (const float*)d_in[9];
  const float* bs = (const float*)d_in[10];

  char* wsp = (char*)d_ws;
  float* Mm32 = (float*)(wsp);            //  17408 B
  float* Ms32 = (float*)(wsp + 17408);    //  32768 B
  float* Mb32 = (float*)(wsp + 50176);    //  65536 B
  float* MmT  = (float*)(wsp + 115712);   //  17408 B
  float* MsT  = (float*)(wsp + 133120);   //  32768 B
  u16*   lut  = (u16*)(wsp + 165888);     // 524288 B -> total 690176 B

  precompute_M<<<128, 256, 0, stream>>>(embed, Wm, bm, Wb, bb, Ws, bs,
                                        Mm32, Ms32, Mb32, MmT, MsT);
  build_lut<<<2048, 128, 0, stream>>>(Wm, Ws, MmT, MsT, lut);
  sm_fused<<<512, 512, 0, stream>>>(x, tactp, tstp, forcp, lut,
                                    Wm, Wb, Ws, Mm32, Ms32, Mb32,
                                    (float*)d_out);
}

// Round 33
// 141.118 us; speedup vs baseline: 1.0314x; 1.0175x over previous
//
#include <hip/hip_runtime.h>
#include <stdint.h>
#include <limits.h>

// StackMachineCell — fused, 1-block/CU topology A/B (round 33).
// r32 null (DS-op count not binding). r30 best (140.9). Budget: non-forced
// step ~1000cy >> warm-L2 225cy -> producer may be ISSUE-STARVED: at 512
// blocks (2/CU, 16 waves/CU) the producer shares its SIMD with 3 waves.
// This round: r30 verbatim at 256 blocks x 512t, 2 chains/block (waves 0-1
// producers, waves 2-7 consumers 3/chain — r22's proven balance) -> 1
// block/CU, producer shares with just 1 consumer wave. Warmup split over 6
// waves. All semantics byte-identical to r30 (PASSED, absmax 0.0009765625).
// ws: Mm32@0 | Ms32@17408 | Mb32@50176 | MmT@115712 | MsT@133120 |
//     lut@165888  (total 690176 B; guarded).

#define TT 512
#define BB 512
#define HH 128
#define NSs 64
#define NMm 34
#define NBb 128

typedef unsigned short u16;
typedef float f2 __attribute__((ext_vector_type(2)));

// ---- precompute M tables (f64 accumulate, f32 store; + transposed copies)
__global__ __launch_bounds__(256) void precompute_M(
    const float* __restrict__ embed,
    const float* __restrict__ Wm, const float* __restrict__ bm,
    const float* __restrict__ Wb, const float* __restrict__ bb,
    const float* __restrict__ Ws, const float* __restrict__ bs,
    float* __restrict__ Mm32, float* __restrict__ Ms32,
    float* __restrict__ Mb32, float* __restrict__ MmT,
    float* __restrict__ MsT) {
  __shared__ double e[HH];
  const int v = blockIdx.x;
  const int tid = threadIdx.x;  // 256
  if (tid < HH) e[tid] = (double)embed[v * HH + tid];
  __syncthreads();
  if (tid < NMm) {
    const int j = tid;
    double acc = 0.0;
    for (int h = 0; h < HH; ++h) acc += e[h] * (double)Wm[h * NMm + j];
    const float r = (float)(acc + (double)bm[j]);
    Mm32[v * NMm + j] = r;
    MmT[j * 128 + v] = r;
  } else if (tid < NMm + NSs) {
    const int j = tid - NMm;
    double acc = 0.0;
    for (int h = 0; h < HH; ++h) acc += e[h] * (double)Ws[h * NSs + j];
    const float r = (float)(acc + (double)bs[j]);
    Ms32[v * NSs + j] = r;
    MsT[j * 128 + v] = r;
  } else if (tid < NMm + NSs + NBb) {
    const int j = tid - NMm - NSs;
    double acc = 0.0;
    for (int h = 0; h < HH; ++h) acc += e[h] * (double)Wb[h * NBb + j];
    Mb32[v * NBb + j] = (float)(acc + (double)bb[j]);
  }
}

// ---- build decision LUT: block = (s,r) pair, thread = v. Bit-identical
// arithmetic to r12-r32. Layout lut[(s*32+r)*128 + v] (u16).
__global__ __launch_bounds__(128) void build_lut(
    const float* __restrict__ Wm, const float* __restrict__ Ws,
    const float* __restrict__ MmT, const float* __restrict__ MsT,
    u16* __restrict__ lut) {
  __shared__ float wms[NMm], wmr[NMm], wss[NSs], wsr[NSs];  // 784 B
  const int s = blockIdx.x >> 5;    // 0..63
  const int r = blockIdx.x & 31;    // 0..31
  const int tid = threadIdx.x;      // 128 = one v per thread
  if (tid < NMm) {
    wms[tid] = Wm[(128 + s) * NMm + tid];
    wmr[tid] = Wm[(192 + r) * NMm + tid];
  }
  if (tid < NSs) {
    wss[tid] = Ws[(128 + s) * NSs + tid];
    wsr[tid] = Ws[(192 + r) * NSs + tid];
  }
  __syncthreads();

  const int v = tid;
  int bestm = INT_MIN, act = 0;
#pragma unroll
  for (int j = 0; j < NMm; ++j) {
    const double val = (double)MmT[j * 128 + v] + (double)wms[j] + (double)wmr[j];
    const int iv = (int)(val * 67108864.0);
    if (iv > bestm) { bestm = iv; act = j; }
  }
  int bests = INT_MIN, ns = 0;
#pragma unroll
  for (int j = 0; j < NSs; ++j) {
    const double val = (double)MsT[j * 128 + v] + (double)wss[j] + (double)wsr[j];
    const int iv = (int)(val * 67108864.0);
    if (iv > bests) { bests = iv; ns = j; }
  }
  lut[(unsigned)blockIdx.x * 128 + v] = (u16)(act | (ns << 6));
}

// ---- fused: 256 blocks x 512 threads, TWO chains per block (1 block/CU).
// Waves 0-1 = producers (r30 chain verbatim, setprio 1); waves 2-7 =
// consumers (3 per chain, warmup sweep, rows t mod 3, nt stores).
// trajL doubles as progress flag (0xFFFF = not ready; legal <= 0x1F3F).
__global__ __launch_bounds__(512, 1) void sm_fused(
    const int* __restrict__ x, const int* __restrict__ tact,
    const int* __restrict__ tstate, const int* __restrict__ forc,
    const u16* __restrict__ lut,
    const float* __restrict__ Wm, const float* __restrict__ Wb,
    const float* __restrict__ Ws,
    const float* __restrict__ Mm32, const float* __restrict__ Ms32,
    const float* __restrict__ Mb32, float* __restrict__ out) {
  __shared__ unsigned sPk[2][TT];          // 4096 B
  __shared__ volatile u16 trajL[2][TT];    // 2048 B (flag+data in one u16)
  const int tid = threadIdx.x;
  const int base = blockIdx.x * 2;
  for (int i = tid; i < 2 * TT; i += 512) {
    const int c = i >> 9, t = i & (TT - 1);
    const int g = t * BB + base + c;
    sPk[c][t] = (unsigned)x[g] | ((unsigned)tact[g] << 8) |
                ((unsigned)tstate[g] << 16) | ((unsigned)forc[g] << 24);
    trajL[c][t] = 0xFFFFu;
  }
  __syncthreads();  // last barrier; roles diverge below

  const int lane = tid & 63;
  const int w = tid >> 6;

  if (w < 2) {
    // ===== producer: r30 chain verbatim =================================
    __builtin_amdgcn_s_setprio(1);
    const int c = w;
    int stackv = 0;  // lane i holds stack[i]
    int ptr = 0, rr = 0, s = 0;
    unsigned p0 = sPk[c][0], p1 = sPk[c][1], p2 = sPk[c][2];

    for (int t = 0; t < TT; ++t) {
      const unsigned p3 = sPk[c][t + 3 < TT ? t + 3 : TT - 1];
      const unsigned pk_s = __builtin_amdgcn_readfirstlane(p0);

      if (lane == 0) trajL[c][t] = (u16)(s | (rr << 8));  // publish carry-in

      int act, ns;
      if (pk_s >> 24) {  // forced: extract from VGPR p0, no LUT
        act = (int)((p0 >> 8) & 63u);
        ns = (int)((p0 >> 16) & 63u);
      } else {
        const int idx = s * 4096 + rr * 128 + (int)(p0 & 127u);
        const int lv = lut[idx];  // vector load — L2-warm after sweep
        act = lv & 63;
        ns = (lv >> 6) & 63;
      }

      const bool ispush = act >= 2;
      int npn = ptr + (ispush ? 1 : 0) - (act == 1 ? 1 : 0);
      npn = npn < 0 ? 0 : (npn > 63 ? 63 : npn);
      if (ispush && lane == npn) stackv = act - 2;
      rr = __builtin_amdgcn_ds_bpermute(npn * 4, stackv);
      ptr = npn;
      s = ns;

      p0 = p1; p1 = p2; p2 = p3;
    }
  } else {
    // ======= consumer: warm local-XCD L2, then rows t = j mod 3 =========
    const int c = (w - 2) & 1;
    const int j = (w - 2) >> 1;      // 0,1,2
    const int b = base + c;
    const int cidx = (w - 2) * 64 + lane;  // 0..383
    // LUT warmup sweep: 512KB as 32768 uint4; coalesced per-wave reads.
    {
      const uint4* lut4 = (const uint4*)lut;
      unsigned acc = 0;
      for (int i = cidx; i < 32768; i += 384) {
        const uint4 vv = lut4[i];
        acc ^= vv.x ^ vv.y ^ vv.z ^ vv.w;
      }
      asm volatile("" : : "v"(acc));  // keep the sweep alive (no DCE)
    }

    float* outLM = out;                                  // [T,B,34]
    float* outLB = out + (size_t)TT * BB * NMm;          // [T,B,128]
    float* outLS = out + (size_t)TT * BB * (NMm + NBb);  // [T,B,64]

    for (int t = j; t < TT; t += 3) {
      int pr = trajL[c][t];
      while (pr == 0xFFFF) {            // flag: row not yet published
        __builtin_amdgcn_s_sleep(4);
        pr = trajL[c][t];
      }
      const unsigned pk = sPk[c][t];
      const int xv = (int)(pk & 127u);
      const int s = pr & 255;
      const int r = pr >> 8;
      const int rs = 128 + s, rr = 192 + r;
      const int row = t * BB + b;
      if (lane < NMm)
        __builtin_nontemporal_store(
            Mm32[xv * NMm + lane] + Wm[rs * NMm + lane] + Wm[rr * NMm + lane],
            &outLM[(size_t)row * NMm + lane]);
      __builtin_nontemporal_store(
          Ms32[xv * NSs + lane] + Ws[rs * NSs + lane] + Ws[rr * NSs + lane],
          &outLS[(size_t)row * NSs + lane]);
      const f2 mb  = *(const f2*)&Mb32[xv * NBb + 2 * lane];
      const f2 wbs = *(const f2*)&Wb[rs * NBb + 2 * lane];
      const f2 wbr = *(const f2*)&Wb[rr * NBb + 2 * lane];
      f2 o;
      o.x = mb.x + wbs.x + wbr.x;   // same per-element add order as r14-r32
      o.y = mb.y + wbs.y + wbr.y;
      __builtin_nontemporal_store(o, (f2*)&outLB[(size_t)row * NBb + 2 * lane]);
    }
  }
}

extern "C" void kernel_launch(void* const* d_in, const int* in_sizes, int n_in,
                              void* d_out, int out_size, void* d_ws, size_t ws_size,
                              hipStream_t stream) {
  if (ws_size < 690176) return;  // signature: absmax 0.3457 -> ws too small

  const int* x     = (const int*)d_in[0];
  const int* tactp = (const int*)d_in[1];
  const int* tstp  = (const int*)d_in[2];
  const int* forcp = (const int*)d_in[3];
  const float* embed = (const float*)d_in[4];
  const float* Wm = (const float*)d_in[5];
  const float* bm = (const float*)d_in[6];
  const float* Wb = (const float*)d_in[7];
  const float* bb = (const float*)d_in[8];
  const float* Ws = (const float*)d_in[9];
  const float* bs = (const float*)d_in[10];

  char* wsp = (char*)d_ws;
  float* Mm32 = (float*)(wsp);            //  17408 B
  float* Ms32 = (float*)(wsp + 17408);    //  32768 B
  float* Mb32 = (float*)(wsp + 50176);    //  65536 B
  float* MmT  = (float*)(wsp + 115712);   //  17408 B
  float* MsT  = (float*)(wsp + 133120);   //  32768 B
  u16*   lut  = (u16*)(wsp + 165888);     // 524288 B -> total 690176 B

  precompute_M<<<128, 256, 0, stream>>>(embed, Wm, bm, Wb, bb, Ws, bs,
                                        Mm32, Ms32, Mb32, MmT, MsT);
  build_lut<<<2048, 128, 0, stream>>>(Wm, Ws, MmT, MsT, lut);
  sm_fused<<<256, 512, 0, stream>>>(x, tactp, tstp, forcp, lut,
                                    Wm, Wb, Ws, Mm32, Ms32, Mb32,
                                    (float*)d_out);
}